// Round 5
// baseline (1516.478 us; speedup 1.0000x reference)
//
#include <hip/hip_runtime.h>
#include <hip/hip_fp16.h>

#define NH 4      // heads
#define CH 64     // channels/head
#define PPART 16  // src slices; fp16 slice = N/16 rows * 512B ~ 1.6MB << 4MB XCD L2

// ---------------- encoder: h = relu(x @ W + b); x:[N,8], W:[8,64] ----------------
__global__ void encoder_kernel(const float* __restrict__ x, const float* __restrict__ W,
                               const float* __restrict__ b, float* __restrict__ h, int N) {
  int idx = blockIdx.x * blockDim.x + threadIdx.x;
  if (idx >= N * 64) return;
  int n = idx >> 6, j = idx & 63;
  const float* xp = x + n * 8;
  float acc = b[j];
#pragma unroll
  for (int k = 0; k < 8; ++k) acc = fmaf(xp[k], W[k * 64 + j], acc);
  h[idx] = fmaxf(acc, 0.0f);
}

// ---------------- xl = h@Wl + bl, xr = h@Wr + br; both stored fp16 ----------------
template <int K>
__global__ void lin_lr_kernel(const float* __restrict__ h,
                              const float* __restrict__ Wl, const float* __restrict__ bl,
                              const float* __restrict__ Wr, const float* __restrict__ br,
                              __half* __restrict__ xl, __half* __restrict__ xr, int N) {
  __shared__ float hs[8][K];
  int n0 = blockIdx.x * 8;
  int j = threadIdx.x;  // output column
  int nmax = N - n0; if (nmax > 8) nmax = 8;
  for (int idx = j; idx < nmax * K; idx += 256) {
    int m = idx / K, k = idx % K;
    hs[m][k] = h[(size_t)(n0 + m) * K + k];
  }
  __syncthreads();
  float accl[8], accr[8];
  float bjl = bl[j], bjr = br[j];
#pragma unroll
  for (int m = 0; m < 8; ++m) { accl[m] = bjl; accr[m] = bjr; }
  for (int k = 0; k < K; ++k) {
    float wl = Wl[k * 256 + j];
    float wr = Wr[k * 256 + j];
#pragma unroll
    for (int m = 0; m < 8; ++m) {
      accl[m] = fmaf(hs[m][k], wl, accl[m]);
      accr[m] = fmaf(hs[m][k], wr, accr[m]);
    }
  }
  for (int m = 0; m < nmax; ++m) {
    xl[(size_t)(n0 + m) * 256 + j] = __float2half_rn(accl[m]);
    xr[(size_t)(n0 + m) * 256 + j] = __float2half_rn(accr[m]);
  }
}

// ---------------- CSR build, counting sort keyed (dst*16 + src_slice) ----------------
__global__ void hist2_kernel(const int* __restrict__ src, const int* __restrict__ dst,
                             int* __restrict__ deg2, int E, int psz) {
  int e = blockIdx.x * blockDim.x + threadIdx.x;
  if (e < E) atomicAdd(&deg2[dst[e] * PPART + src[e] / psz], 1);
}

// A: per-block sum of 4096 deg entries (256 thr x 16); M=16N=800k -> 196 blocks
__global__ void scan_partial16_kernel(const int* __restrict__ deg, int* __restrict__ partial, int M) {
  __shared__ int sm[256];
  int t = threadIdx.x;
  int base = blockIdx.x * 4096 + t * 16;
  int s = 0;
#pragma unroll
  for (int k = 0; k < 16; ++k) { int i = base + k; s += (i < M) ? deg[i] : 0; }
  sm[t] = s;
  __syncthreads();
#pragma unroll
  for (int st = 128; st > 0; st >>= 1) {
    if (t < st) sm[t] += sm[t + st];
    __syncthreads();
  }
  if (t == 0) partial[blockIdx.x] = sm[0];
}

// B: single-block exclusive scan of the (<=256) partials
__global__ void scan_offsets_kernel(int* __restrict__ partial, int nb) {
  __shared__ int sm[256];
  int t = threadIdx.x;
  int v = (t < nb) ? partial[t] : 0;
  sm[t] = v;
  __syncthreads();
#pragma unroll
  for (int off = 1; off < 256; off <<= 1) {
    int a = (t >= off) ? sm[t - off] : 0;
    __syncthreads();
    sm[t] += a;
    __syncthreads();
  }
  if (t < nb) partial[t] = sm[t] - v;  // exclusive
}

// C: per-block scan of 4096 entries + block offset -> rowptr2/cursor2 (in-place safe:
// each block reads its own range into registers before writing)
__global__ void scan_final16_kernel(const int* __restrict__ deg, const int* __restrict__ partial,
                                    int* __restrict__ rowptr, int* __restrict__ cursor, int M, int E) {
  __shared__ int sm[256];
  int t = threadIdx.x;
  int base = blockIdx.x * 4096 + t * 16;
  int v[16]; int s = 0;
#pragma unroll
  for (int k = 0; k < 16; ++k) { int i = base + k; v[k] = (i < M) ? deg[i] : 0; s += v[k]; }
  sm[t] = s;
  __syncthreads();
#pragma unroll
  for (int off = 1; off < 256; off <<= 1) {
    int a = (t >= off) ? sm[t - off] : 0;
    __syncthreads();
    sm[t] += a;
    __syncthreads();
  }
  int run = partial[blockIdx.x] + sm[t] - s;  // exclusive base for this thread's 16
#pragma unroll
  for (int k = 0; k < 16; ++k) {
    int i = base + k;
    if (i < M) { rowptr[i] = run; cursor[i] = run; run += v[k]; }
  }
  if (blockIdx.x == 0 && t == 0) rowptr[M] = E;
}

__global__ void scatter_build2_kernel(const int* __restrict__ src, const int* __restrict__ dst,
                                      const float* __restrict__ ea, int* __restrict__ cursor,
                                      int* __restrict__ srcs, float* __restrict__ eas, int E, int psz) {
  int e = blockIdx.x * blockDim.x + threadIdx.x;
  if (e >= E) return;
  int s = src[e];
  int key = dst[e] * PPART + s / psz;
  int pos = atomicAdd(&cursor[key], 1);
  srcs[pos] = s;
  eas[pos] = ea[e];
}

// ---------------- helpers: fp16x4 -> float4 ----------------
__device__ __forceinline__ float4 ldh4(const uint2* __restrict__ p, size_t idx) {
  uint2 r = p[idx];
  __half2 a = *reinterpret_cast<const __half2*>(&r.x);
  __half2 b = *reinterpret_cast<const __half2*>(&r.y);
  float2 fa = __half22float2(a);
  float2 fb = __half22float2(b);
  return make_float4(fa.x, fa.y, fb.x, fb.y);
}

// ---------------- per-edge alpha + accumulate (unchanged math) ----------------
__device__ __forceinline__ void edge_accum(const float4 xlv, const float eav,
                                           const float4 xr4, const float4 We4, const float4 at4,
                                           float4& acc, float& denom) {
  float4 v;
  v.x = fmaf(eav, We4.x, xlv.x + xr4.x);
  v.y = fmaf(eav, We4.y, xlv.y + xr4.y);
  v.z = fmaf(eav, We4.z, xlv.z + xr4.z);
  v.w = fmaf(eav, We4.w, xlv.w + xr4.w);
  v.x = (v.x >= 0.f) ? v.x : 0.2f * v.x;
  v.y = (v.y >= 0.f) ? v.y : 0.2f * v.y;
  v.z = (v.z >= 0.f) ? v.z : 0.2f * v.z;
  v.w = (v.w >= 0.f) ? v.w : 0.2f * v.w;
  float p = v.x * at4.x + v.y * at4.y + v.z * at4.z + v.w * at4.w;
  p += __shfl_xor(p, 1, 64);
  p += __shfl_xor(p, 2, 64);
  p += __shfl_xor(p, 4, 64);
  p += __shfl_xor(p, 8, 64);   // all 16 lanes of the head group hold alpha_h
  float ex = __expf(p);
  denom += ex;
  acc.x = fmaf(ex, xlv.x, acc.x);
  acc.y = fmaf(ex, xlv.y, acc.y);
  acc.z = fmaf(ex, xlv.z, acc.z);
  acc.w = fmaf(ex, xlv.w, acc.w);
}

// ---------------- fused GATv2: slice-phase-coherent sweep, acc in registers ----------------
// One wave owns 8 consecutive nodes; acc[8] (float4) + den[8] stay in VGPRs.
// Edges are CSR-sorted by (dst, src-slice); every wave sweeps slices 0..15 in the
// same order. With __launch_bounds__(256,6), 24 waves/CU * 256 CU = 6144 resident
// waves ~= all ceil(N/8)=6250 waves: one resident generation, so the population
// stays loosely slice-phase-coherent (no sync needed for correctness -- purely a
// locality effect). Instantaneous gather working set ~2 slices = 3.2MB < 4MB L2.
template <bool POOL>
__global__ __launch_bounds__(256, 6)
void gat_sweep_kernel(const int* __restrict__ rowptr2,
                      const int* __restrict__ srcs,
                      const float* __restrict__ eas,
                      const __half* __restrict__ xl,
                      const __half* __restrict__ xr,
                      const float* __restrict__ We,
                      const float* __restrict__ att,
                      const float* __restrict__ bias,
                      float* __restrict__ out,
                      const int* __restrict__ batch,
                      float* __restrict__ sums,
                      float* __restrict__ cnt,
                      int N) {
  int gw = (int)((blockIdx.x * (size_t)blockDim.x + threadIdx.x) >> 6);
  int lane = threadIdx.x & 63;
  int d0 = gw * 8;
  if (d0 >= N) return;
  const uint2* xlh = (const uint2*)xl;
  const uint2* xrh = (const uint2*)xr;
  float4 We4 = ((const float4*)We)[lane];
  float4 at4 = ((const float4*)att)[lane];
  float4 acc[8];
  float den[8];
#pragma unroll
  for (int n = 0; n < 8; ++n) { acc[n] = make_float4(0.f, 0.f, 0.f, 0.f); den[n] = 0.f; }
  for (int s = 0; s < PPART; ++s) {
#pragma unroll
    for (int n = 0; n < 8; ++n) {
      int dd = d0 + n;
      if (dd < N) {
        int beg = rowptr2[dd * PPART + s];
        int end = rowptr2[dd * PPART + s + 1];
        if (beg < end) {
          float4 xr4 = ldh4(xrh, (size_t)dd * 64 + lane);  // L2-warm after slice 0
          for (int i = beg; i < end; ++i) {
            int sv = srcs[i];
            float ev = eas[i];
            float4 a0 = ldh4(xlh, (size_t)sv * 64 + lane); // confined to slice s
            edge_accum(a0, ev, xr4, We4, at4, acc[n], den[n]);
          }
        }
      }
    }
  }
  float4 b4 = ((const float4*)bias)[lane];
#pragma unroll
  for (int n = 0; n < 8; ++n) {
    int dd = d0 + n;
    if (dd < N) {
      float inv = 1.f / (den[n] + 1e-16f);
      float4 o;
      o.x = fmaxf(fmaf(acc[n].x, inv, b4.x), 0.f);
      o.y = fmaxf(fmaf(acc[n].y, inv, b4.y), 0.f);
      o.z = fmaxf(fmaf(acc[n].z, inv, b4.z), 0.f);
      o.w = fmaxf(fmaf(acc[n].w, inv, b4.w), 0.f);
      if (POOL) {
        int g = batch[dd];
        float* sg = sums + (size_t)g * 256 + lane * 4;
        atomicAdd(sg + 0, o.x);
        atomicAdd(sg + 1, o.y);
        atomicAdd(sg + 2, o.z);
        atomicAdd(sg + 3, o.w);
        if (lane == 0) atomicAdd(&cnt[g], 1.0f);
      } else {
        ((float4*)out)[(size_t)dd * 64 + lane] = o;
      }
    }
  }
}

// ---------------- per-graph MLP head ----------------
__global__ void mlp_kernel(const float* __restrict__ sums, const float* __restrict__ cnt,
                           const float* __restrict__ p1W, const float* __restrict__ p1b,
                           const float* __restrict__ lng, const float* __restrict__ lnb,
                           const float* __restrict__ p2W, const float* __restrict__ p2b,
                           float* __restrict__ outp, int G) {
  __shared__ float p[256];
  __shared__ float z[128];
  __shared__ float wsum[2];
  __shared__ float wsum2[2];
  int g = blockIdx.x;
  int t = threadIdx.x;  // 0..127
  float c = fmaxf(cnt[g], 1.0f);
  p[t] = sums[(size_t)g * 256 + t] / c;
  p[t + 128] = sums[(size_t)g * 256 + t + 128] / c;
  __syncthreads();
  float acc = p1b[t];
  for (int k = 0; k < 256; ++k) acc = fmaf(p[k], p1W[k * 128 + t], acc);
  float v = acc;
#pragma unroll
  for (int off = 32; off > 0; off >>= 1) v += __shfl_xor(v, off, 64);
  if ((t & 63) == 0) wsum[t >> 6] = v;
  __syncthreads();
  float mu = (wsum[0] + wsum[1]) * (1.0f / 128.0f);
  float dv = acc - mu;
  float vv = dv * dv;
#pragma unroll
  for (int off = 32; off > 0; off >>= 1) vv += __shfl_xor(vv, off, 64);
  if ((t & 63) == 0) wsum2[t >> 6] = vv;
  __syncthreads();
  float var = (wsum2[0] + wsum2[1]) * (1.0f / 128.0f);
  float zv = dv * rsqrtf(var + 1e-5f) * lng[t] + lnb[t];
  z[t] = fmaxf(zv, 0.0f);
  __syncthreads();
  if (t < 64) {
    float o = p2b[t];
    for (int k = 0; k < 128; ++k) o = fmaf(z[k], p2W[k * 64 + t], o);
    outp[(size_t)g * 64 + t] = fmaxf(o, 0.0f);
  }
}

extern "C" void kernel_launch(void* const* d_in, const int* in_sizes, int n_in,
                              void* d_out, int out_size, void* d_ws, size_t ws_size,
                              hipStream_t stream) {
  const float* x      = (const float*)d_in[0];
  const int*   ei     = (const int*)d_in[1];
  const float* ea     = (const float*)d_in[2];
  const int*   batch  = (const int*)d_in[3];
  const float* enc_W  = (const float*)d_in[4];
  const float* enc_b  = (const float*)d_in[5];
  const float* Wl1    = (const float*)d_in[6];
  const float* bl1    = (const float*)d_in[7];
  const float* Wr1    = (const float*)d_in[8];
  const float* br1    = (const float*)d_in[9];
  const float* We1    = (const float*)d_in[10];
  const float* att1   = (const float*)d_in[11];
  const float* bias1  = (const float*)d_in[12];
  const float* Wl2    = (const float*)d_in[13];
  const float* bl2    = (const float*)d_in[14];
  const float* Wr2    = (const float*)d_in[15];
  const float* br2    = (const float*)d_in[16];
  const float* We2    = (const float*)d_in[17];
  const float* att2   = (const float*)d_in[18];
  const float* bias2  = (const float*)d_in[19];
  const float* p1W    = (const float*)d_in[20];
  const float* p1b    = (const float*)d_in[21];
  const float* lng    = (const float*)d_in[22];
  const float* lnb    = (const float*)d_in[23];
  const float* p2W    = (const float*)d_in[24];
  const float* p2b    = (const float*)d_in[25];
  float* outp = (float*)d_out;

  int N = in_sizes[0] / 8;
  int E = in_sizes[2];
  int G = out_size / 64;
  const int* src = ei;
  const int* dst = ei + E;
  int M = N * PPART;                 // 16N keys (N=50000 -> 800k)
  int psz = (N + PPART - 1) / PPART; // src rows per slice (3125)
  int nb2 = (M + 4095) / 4096;       // scan blocks over M (<=256; 800k -> 196)

  // ---- workspace layout (~128MB, below the proven 173MB footprint) ----
  float* ws      = (float*)d_ws;
  float* h0      = ws;                          // N*64 f32
  __half* xlh    = (__half*)(h0 + (size_t)N * 64);           // N*256 fp16
  __half* xrh    = (__half*)((float*)xlh + (size_t)N * 128); // N*256 fp16
  float* B2      = (float*)xrh + (size_t)N * 128;            // N*256 f32 (layer1 out)
  float* eas     = B2     + (size_t)N * 256;    // E floats (sorted edge attr)
  float* sums    = eas    + (size_t)E;          // G*256
  float* cnt     = sums   + (size_t)G * 256;    // G
  int*   srcs    = (int*)(cnt + G);             // E ints (sorted src)
  int*   rowptr2 = srcs + (size_t)E;            // M+1
  int*   cursor2 = rowptr2 + (size_t)(M + 1);   // M (doubles as deg2 histogram)
  int*   partial = cursor2 + (size_t)M;         // nb2 (<=256)

  // encoder
  encoder_kernel<<<(N * 64 + 255) / 256, 256, 0, stream>>>(x, enc_W, enc_b, h0, N);

  // CSR build keyed (dst, src-slice) — shared by both layers (edge_index static)
  hipMemsetAsync(cursor2, 0, (size_t)M * sizeof(int), stream);
  hist2_kernel<<<(E + 255) / 256, 256, 0, stream>>>(src, dst, cursor2, E, psz);
  scan_partial16_kernel<<<nb2, 256, 0, stream>>>(cursor2, partial, M);
  scan_offsets_kernel<<<1, 256, 0, stream>>>(partial, nb2);
  scan_final16_kernel<<<nb2, 256, 0, stream>>>(cursor2, partial, rowptr2, cursor2, M, E);
  scatter_build2_kernel<<<(E + 255) / 256, 256, 0, stream>>>(src, dst, ea, cursor2, srcs, eas, E, psz);

  int nwav = (N + 7) / 8;            // waves for the sweep (6250)
  int nblk = (nwav + 3) / 4;         // 4 waves per block (1563)

  // GAT layer 1 (K=64): h0 -> B2
  lin_lr_kernel<64><<<(N + 7) / 8, 256, 0, stream>>>(h0, Wl1, bl1, Wr1, br1, xlh, xrh, N);
  gat_sweep_kernel<false><<<nblk, 256, 0, stream>>>(
      rowptr2, srcs, eas, xlh, xrh, We1, att1, bias1, B2, nullptr, nullptr, nullptr, N);

  // GAT layer 2 (K=256): B2 -> pooled sums directly
  lin_lr_kernel<256><<<(N + 7) / 8, 256, 0, stream>>>(B2, Wl2, bl2, Wr2, br2, xlh, xrh, N);
  hipMemsetAsync(sums, 0, ((size_t)G * 256 + G) * sizeof(float), stream);
  gat_sweep_kernel<true><<<nblk, 256, 0, stream>>>(
      rowptr2, srcs, eas, xlh, xrh, We2, att2, bias2, nullptr, batch, sums, cnt, N);

  // per-graph MLP
  mlp_kernel<<<G, 128, 0, stream>>>(sums, cnt, p1W, p1b, lng, lnb, p2W, p2b, outp, G);
}

// Round 6
// 1071.669 us; speedup vs baseline: 1.4151x; 1.4151x over previous
//
#include <hip/hip_runtime.h>
#include <hip/hip_fp16.h>

#define NH 4     // heads
#define CH 64    // channels/head

// ---------------- encoder: h = relu(x @ W + b); x:[N,8], W:[8,64] ----------------
__global__ void encoder_kernel(const float* __restrict__ x, const float* __restrict__ W,
                               const float* __restrict__ b, float* __restrict__ h, int N) {
  int idx = blockIdx.x * blockDim.x + threadIdx.x;
  if (idx >= N * 64) return;
  int n = idx >> 6, j = idx & 63;
  const float* xp = x + n * 8;
  float acc = b[j];
#pragma unroll
  for (int k = 0; k < 8; ++k) acc = fmaf(xp[k], W[k * 64 + j], acc);
  h[idx] = fmaxf(acc, 0.0f);
}

// ---------------- xl = h@Wl + bl, xr = h@Wr + br; both stored fp16 ----------------
// fp16 rows (512B) let the aggregate kernel fetch TWO edge rows per dwordx4 instr.
template <int K>
__global__ void lin_lr_kernel(const float* __restrict__ h,
                              const float* __restrict__ Wl, const float* __restrict__ bl,
                              const float* __restrict__ Wr, const float* __restrict__ br,
                              __half* __restrict__ xl, __half* __restrict__ xr, int N) {
  __shared__ float hs[8][K];
  int n0 = blockIdx.x * 8;
  int j = threadIdx.x;  // output column
  int nmax = N - n0; if (nmax > 8) nmax = 8;
  for (int idx = j; idx < nmax * K; idx += 256) {
    int m = idx / K, k = idx % K;
    hs[m][k] = h[(size_t)(n0 + m) * K + k];
  }
  __syncthreads();
  float accl[8], accr[8];
  float bjl = bl[j], bjr = br[j];
#pragma unroll
  for (int m = 0; m < 8; ++m) { accl[m] = bjl; accr[m] = bjr; }
  for (int k = 0; k < K; ++k) {
    float wl = Wl[k * 256 + j];
    float wr = Wr[k * 256 + j];
#pragma unroll
    for (int m = 0; m < 8; ++m) {
      accl[m] = fmaf(hs[m][k], wl, accl[m]);
      accr[m] = fmaf(hs[m][k], wr, accr[m]);
    }
  }
  for (int m = 0; m < nmax; ++m) {
    xl[(size_t)(n0 + m) * 256 + j] = __float2half_rn(accl[m]);
    xr[(size_t)(n0 + m) * 256 + j] = __float2half_rn(accr[m]);
  }
}

// ---------------- CSR build (counting sort by dst), fully parallel scan ----------------
__global__ void hist_kernel(const int* __restrict__ dst, int* __restrict__ deg, int E) {
  int e = blockIdx.x * blockDim.x + threadIdx.x;
  if (e < E) atomicAdd(&deg[dst[e]], 1);
}

__global__ void scan_partial_kernel(const int* __restrict__ deg, int* __restrict__ partial, int N) {
  __shared__ int sm[256];
  int t = threadIdx.x;
  int i = blockIdx.x * 256 + t;
  sm[t] = (i < N) ? deg[i] : 0;
  __syncthreads();
#pragma unroll
  for (int s = 128; s > 0; s >>= 1) {
    if (t < s) sm[t] += sm[t + s];
    __syncthreads();
  }
  if (t == 0) partial[blockIdx.x] = sm[0];
}

__global__ void scan_offsets_kernel(int* __restrict__ partial, int nb) {
  __shared__ int sm[256];
  int t = threadIdx.x;
  int v = (t < nb) ? partial[t] : 0;
  sm[t] = v;
  __syncthreads();
#pragma unroll
  for (int off = 1; off < 256; off <<= 1) {
    int a = (t >= off) ? sm[t - off] : 0;
    __syncthreads();
    sm[t] += a;
    __syncthreads();
  }
  if (t < nb) partial[t] = sm[t] - v;  // exclusive
}

__global__ void scan_final_kernel(const int* __restrict__ deg, const int* __restrict__ partial,
                                  int* __restrict__ rowptr, int* __restrict__ cursor, int N, int E) {
  __shared__ int sm[256];
  int t = threadIdx.x;
  int i = blockIdx.x * 256 + t;
  int v = (i < N) ? deg[i] : 0;
  sm[t] = v;
  __syncthreads();
#pragma unroll
  for (int off = 1; off < 256; off <<= 1) {
    int a = (t >= off) ? sm[t - off] : 0;
    __syncthreads();
    sm[t] += a;
    __syncthreads();
  }
  if (i < N) {
    int ex = partial[blockIdx.x] + sm[t] - v;
    rowptr[i] = ex;
    cursor[i] = ex;
  }
  if (i == 0) rowptr[N] = E;
}

__global__ void scatter_build_kernel(const int* __restrict__ src, const int* __restrict__ dst,
                                     const float* __restrict__ ea, int* __restrict__ cursor,
                                     int* __restrict__ srcs, float* __restrict__ eas, int E) {
  int e = blockIdx.x * blockDim.x + threadIdx.x;
  if (e >= E) return;
  int d = dst[e];
  int pos = atomicAdd(&cursor[d], 1);
  srcs[pos] = src[e];
  eas[pos] = ea[e];
}

// ---------------- fused GATv2: 2 edges per gather instruction ----------------
// One wave per node. fp16 xl rows = 512B; one dwordx4/lane (16B) x 64 lanes = 1024B
// = TWO rows: lanes 0..31 hold edge A, lanes 32..63 edge B; each lane holds 8
// channels (lq=lane&31 -> channels 8*lq..8*lq+7, head = lq>>3, 8 lanes/head).
// Per pair: 1 gather inst, 3 shfls (8-lane head reduce), 1 exp inst — vs 2/8/2
// in the per-edge layout. Halves accumulate independently; one cross-half (shfl 32)
// reduce at the end. Odd tail = duplicated pair with hi half masked.
__device__ __forceinline__ void unpack8(const uint4 r, float o[8]) {
  const __half2* hp = reinterpret_cast<const __half2*>(&r);
#pragma unroll
  for (int k = 0; k < 4; ++k) {
    float2 f = __half22float2(hp[k]);
    o[2 * k] = f.x; o[2 * k + 1] = f.y;
  }
}

__device__ __forceinline__ void pair_accum(const uint4 raw, const float eav, const float mask,
                                           const float xr8[8], const float We8[8], const float at8[8],
                                           float acc[8], float& den) {
  float xlv[8];
  unpack8(raw, xlv);
  float p = 0.f;
#pragma unroll
  for (int c = 0; c < 8; ++c) {
    float v = fmaf(eav, We8[c], xlv[c] + xr8[c]);
    v = (v >= 0.f) ? v : 0.2f * v;
    p = fmaf(v, at8[c], p);
  }
  p += __shfl_xor(p, 1, 64);
  p += __shfl_xor(p, 2, 64);
  p += __shfl_xor(p, 4, 64);   // 8-lane head group now holds alpha for its edge
  float ex = __expf(p) * mask;
  den += ex;
#pragma unroll
  for (int c = 0; c < 8; ++c) acc[c] = fmaf(ex, xlv[c], acc[c]);
}

template <bool POOL>
__global__ __launch_bounds__(256)
void gat_aggregate_kernel(const int* __restrict__ rowptr,
                          const int* __restrict__ srcs,
                          const float* __restrict__ eas,
                          const __half* __restrict__ xl,
                          const __half* __restrict__ xr,
                          const float* __restrict__ We,
                          const float* __restrict__ att,
                          const float* __restrict__ bias,
                          float* __restrict__ out,
                          const int* __restrict__ batch,
                          float* __restrict__ sums,
                          float* __restrict__ cnt,
                          int N) {
  int d = (int)((blockIdx.x * (size_t)blockDim.x + threadIdx.x) >> 6);
  int lane = threadIdx.x & 63;
  if (d >= N) return;
  int lq = lane & 31;          // 16B-chunk index within a row
  bool lo = (lane < 32);
  const uint4* xlh8 = (const uint4*)xl;
  const uint4* xrh8 = (const uint4*)xr;
  float xr8[8];
  { uint4 r = xrh8[(size_t)d * 32 + lq]; unpack8(r, xr8); }
  float We8[8], at8[8];
#pragma unroll
  for (int k = 0; k < 8; ++k) { We8[k] = We[lq * 8 + k]; at8[k] = att[lq * 8 + k]; }
  int beg = rowptr[d], end = rowptr[d + 1];
  float acc[8];
#pragma unroll
  for (int c = 0; c < 8; ++c) acc[c] = 0.f;
  float den = 0.f;
  int pend = beg + ((end - beg) & ~1);
  int i = beg;
  for (; i + 7 < pend; i += 8) {   // 4 pair-gathers (8 edges) in flight
    int s0 = srcs[i],     s1 = srcs[i + 1], s2 = srcs[i + 2], s3 = srcs[i + 3];
    int s4 = srcs[i + 4], s5 = srcs[i + 5], s6 = srcs[i + 6], s7 = srcs[i + 7];
    int a0 = lo ? s0 : s1, a1 = lo ? s2 : s3, a2 = lo ? s4 : s5, a3 = lo ? s6 : s7;
    uint4 r0 = xlh8[(size_t)a0 * 32 + lq];
    uint4 r1 = xlh8[(size_t)a1 * 32 + lq];
    uint4 r2 = xlh8[(size_t)a2 * 32 + lq];
    uint4 r3 = xlh8[(size_t)a3 * 32 + lq];
    float e0 = eas[i],     e1 = eas[i + 1], e2 = eas[i + 2], e3 = eas[i + 3];
    float e4 = eas[i + 4], e5 = eas[i + 5], e6 = eas[i + 6], e7 = eas[i + 7];
    float f0 = lo ? e0 : e1, f1 = lo ? e2 : e3, f2 = lo ? e4 : e5, f3 = lo ? e6 : e7;
    pair_accum(r0, f0, 1.f, xr8, We8, at8, acc, den);
    pair_accum(r1, f1, 1.f, xr8, We8, at8, acc, den);
    pair_accum(r2, f2, 1.f, xr8, We8, at8, acc, den);
    pair_accum(r3, f3, 1.f, xr8, We8, at8, acc, den);
  }
  for (; i < pend; i += 2) {
    int s0 = srcs[i], s1 = srcs[i + 1];
    int a0 = lo ? s0 : s1;
    uint4 r0 = xlh8[(size_t)a0 * 32 + lq];
    float f0 = lo ? eas[i] : eas[i + 1];
    pair_accum(r0, f0, 1.f, xr8, We8, at8, acc, den);
  }
  if (pend < end) {              // odd tail: both halves load the edge, hi half masked
    int s0 = srcs[end - 1];
    uint4 r0 = xlh8[(size_t)s0 * 32 + lq];
    float f0 = eas[end - 1];
    pair_accum(r0, f0, lo ? 1.f : 0.f, xr8, We8, at8, acc, den);
  }
  // combine the two half-wave accumulators
  den += __shfl_xor(den, 32, 64);
#pragma unroll
  for (int c = 0; c < 8; ++c) acc[c] += __shfl_xor(acc[c], 32, 64);
  float inv = 1.f / (den + 1e-16f);
  int half = lane >> 5;
  // static-index selects (no runtime-indexed register array -> no scratch)
  float c0 = half ? acc[4] : acc[0];
  float c1 = half ? acc[5] : acc[1];
  float c2 = half ? acc[6] : acc[2];
  float c3 = half ? acc[7] : acc[3];
  float4 b4 = ((const float4*)bias)[lq * 2 + half];
  float4 o;
  o.x = fmaxf(fmaf(c0, inv, b4.x), 0.f);
  o.y = fmaxf(fmaf(c1, inv, b4.y), 0.f);
  o.z = fmaxf(fmaf(c2, inv, b4.z), 0.f);
  o.w = fmaxf(fmaf(c3, inv, b4.w), 0.f);
  if (POOL) {
    int g = batch[d];
    float* sg = sums + (size_t)g * 256 + lq * 8 + half * 4;
    atomicAdd(sg + 0, o.x);
    atomicAdd(sg + 1, o.y);
    atomicAdd(sg + 2, o.z);
    atomicAdd(sg + 3, o.w);
    if (lane == 0) atomicAdd(&cnt[g], 1.0f);
  } else {
    ((float4*)out)[(size_t)d * 64 + lq * 2 + half] = o;
  }
}

// ---------------- per-graph MLP head ----------------
__global__ void mlp_kernel(const float* __restrict__ sums, const float* __restrict__ cnt,
                           const float* __restrict__ p1W, const float* __restrict__ p1b,
                           const float* __restrict__ lng, const float* __restrict__ lnb,
                           const float* __restrict__ p2W, const float* __restrict__ p2b,
                           float* __restrict__ outp, int G) {
  __shared__ float p[256];
  __shared__ float z[128];
  __shared__ float wsum[2];
  __shared__ float wsum2[2];
  int g = blockIdx.x;
  int t = threadIdx.x;  // 0..127
  float c = fmaxf(cnt[g], 1.0f);
  p[t] = sums[(size_t)g * 256 + t] / c;
  p[t + 128] = sums[(size_t)g * 256 + t + 128] / c;
  __syncthreads();
  float acc = p1b[t];
  for (int k = 0; k < 256; ++k) acc = fmaf(p[k], p1W[k * 128 + t], acc);
  float v = acc;
#pragma unroll
  for (int off = 32; off > 0; off >>= 1) v += __shfl_xor(v, off, 64);
  if ((t & 63) == 0) wsum[t >> 6] = v;
  __syncthreads();
  float mu = (wsum[0] + wsum[1]) * (1.0f / 128.0f);
  float dv = acc - mu;
  float vv = dv * dv;
#pragma unroll
  for (int off = 32; off > 0; off >>= 1) vv += __shfl_xor(vv, off, 64);
  if ((t & 63) == 0) wsum2[t >> 6] = vv;
  __syncthreads();
  float var = (wsum2[0] + wsum2[1]) * (1.0f / 128.0f);
  float zv = dv * rsqrtf(var + 1e-5f) * lng[t] + lnb[t];
  z[t] = fmaxf(zv, 0.0f);
  __syncthreads();
  if (t < 64) {
    float o = p2b[t];
    for (int k = 0; k < 128; ++k) o = fmaf(z[k], p2W[k * 64 + t], o);
    outp[(size_t)g * 64 + t] = fmaxf(o, 0.0f);
  }
}

extern "C" void kernel_launch(void* const* d_in, const int* in_sizes, int n_in,
                              void* d_out, int out_size, void* d_ws, size_t ws_size,
                              hipStream_t stream) {
  const float* x      = (const float*)d_in[0];
  const int*   ei     = (const int*)d_in[1];
  const float* ea     = (const float*)d_in[2];
  const int*   batch  = (const int*)d_in[3];
  const float* enc_W  = (const float*)d_in[4];
  const float* enc_b  = (const float*)d_in[5];
  const float* Wl1    = (const float*)d_in[6];
  const float* bl1    = (const float*)d_in[7];
  const float* Wr1    = (const float*)d_in[8];
  const float* br1    = (const float*)d_in[9];
  const float* We1    = (const float*)d_in[10];
  const float* att1   = (const float*)d_in[11];
  const float* bias1  = (const float*)d_in[12];
  const float* Wl2    = (const float*)d_in[13];
  const float* bl2    = (const float*)d_in[14];
  const float* Wr2    = (const float*)d_in[15];
  const float* br2    = (const float*)d_in[16];
  const float* We2    = (const float*)d_in[17];
  const float* att2   = (const float*)d_in[18];
  const float* bias2  = (const float*)d_in[19];
  const float* p1W    = (const float*)d_in[20];
  const float* p1b    = (const float*)d_in[21];
  const float* lng    = (const float*)d_in[22];
  const float* lnb    = (const float*)d_in[23];
  const float* p2W    = (const float*)d_in[24];
  const float* p2b    = (const float*)d_in[25];
  float* outp = (float*)d_out;

  int N = in_sizes[0] / 8;
  int E = in_sizes[2];
  int G = out_size / 64;
  const int* src = ei;
  const int* dst = ei + E;
  int nb = (N + 255) / 256;   // scan blocks (<=256 supported; N=50000 -> 196)

  // ---- workspace layout (~120MB, below the proven 173MB footprint) ----
  float* ws      = (float*)d_ws;
  float* h0      = ws;                          // N*64 f32
  __half* xlh    = (__half*)(h0 + (size_t)N * 64);           // N*256 fp16
  __half* xrh    = (__half*)((float*)xlh + (size_t)N * 128); // N*256 fp16
  float* B2      = (float*)xrh + (size_t)N * 128;            // N*256 f32 (layer1 out)
  float* eas     = B2     + (size_t)N * 256;    // E floats (sorted edge attr)
  float* sums    = eas    + (size_t)E;          // G*256
  float* cnt     = sums   + (size_t)G * 256;    // G
  int*   srcs    = (int*)(cnt + G);             // E ints (sorted src)
  int*   rowptr  = srcs + (size_t)E;            // N+1
  int*   cursor  = rowptr + (size_t)(N + 1);    // N (doubles as deg histogram)
  int*   partial = cursor + (size_t)N;          // nb

  // encoder
  encoder_kernel<<<(N * 64 + 255) / 256, 256, 0, stream>>>(x, enc_W, enc_b, h0, N);

  // CSR build (shared by both layers — dst is static)
  hipMemsetAsync(cursor, 0, (size_t)N * sizeof(int), stream);
  hist_kernel<<<(E + 255) / 256, 256, 0, stream>>>(dst, cursor, E);
  scan_partial_kernel<<<nb, 256, 0, stream>>>(cursor, partial, N);
  scan_offsets_kernel<<<1, 256, 0, stream>>>(partial, nb);
  scan_final_kernel<<<nb, 256, 0, stream>>>(cursor, partial, rowptr, cursor, N, E);
  scatter_build_kernel<<<(E + 255) / 256, 256, 0, stream>>>(src, dst, ea, cursor, srcs, eas, E);

  // GAT layer 1 (K=64): h0 -> B2
  lin_lr_kernel<64><<<(N + 7) / 8, 256, 0, stream>>>(h0, Wl1, bl1, Wr1, br1, xlh, xrh, N);
  gat_aggregate_kernel<false><<<(N + 3) / 4, 256, 0, stream>>>(
      rowptr, srcs, eas, xlh, xrh, We1, att1, bias1, B2, nullptr, nullptr, nullptr, N);

  // GAT layer 2 (K=256): B2 -> pooled sums directly
  lin_lr_kernel<256><<<(N + 7) / 8, 256, 0, stream>>>(B2, Wl2, bl2, Wr2, br2, xlh, xrh, N);
  hipMemsetAsync(sums, 0, ((size_t)G * 256 + G) * sizeof(float), stream);
  gat_aggregate_kernel<true><<<(N + 3) / 4, 256, 0, stream>>>(
      rowptr, srcs, eas, xlh, xrh, We2, att2, bias2, nullptr, batch, sums, cnt, N);

  // per-graph MLP
  mlp_kernel<<<G, 128, 0, stream>>>(sums, cnt, p1W, p1b, lng, lnb, p2W, p2b, outp, G);
}